// Round 1
// baseline (54.665 us; speedup 1.0000x reference)
//
#include <hip/hip_runtime.h>

#define BATCH 262144
#define HIST 100
#define HALF_HIST 50   // float4 loads: 2 timesteps each
#define HIDDEN 128

// Each thread: one batch row.
//  - 50x float4 loads (success,diff pairs), compute 3 features in registers
//  - fused 3->128->32->1 MLP; weights read via wave-uniform indices
//    (compiler emits s_load -> constant cache; no LDS needed)
__global__ __launch_bounds__(256) void competence_kernel(
    const float* __restrict__ hist,
    const float* __restrict__ W1, const float* __restrict__ b1,
    const float* __restrict__ W2, const float* __restrict__ b2,
    const float* __restrict__ W3, const float* __restrict__ b3,
    float* __restrict__ out)
{
    const int row = blockIdx.x * blockDim.x + threadIdx.x;
    if (row >= BATCH) return;

    const float4* __restrict__ h4 =
        (const float4*)(hist + (size_t)row * (HIST * 2));

    float sum = 0.0f, early = 0.0f, recent = 0.0f, maxd = 0.0f;
    #pragma unroll 10
    for (int k = 0; k < HALF_HIST; ++k) {
        float4 v = h4[k];
        // v = (success[2k], diff[2k], success[2k+1], diff[2k+1])
        float s2 = v.x + v.z;
        sum += s2;
        if (k < 10)  early  += s2;   // timesteps 0..19
        if (k >= 40) recent += s2;   // timesteps 80..99
        maxd = fmaxf(maxd, v.x > 0.5f ? v.y : 0.0f);
        maxd = fmaxf(maxd, v.z > 0.5f ? v.w : 0.0f);
    }
    const float f0 = sum * 0.01f;                 // success_rate
    const float f1 = (recent - early) * 0.05f;    // improvement_trend
    const float f2 = maxd;                        // max_difficulty_handled

    // Layer 2 accumulators (32), statically indexed (stay in VGPRs).
    float acc[32];
    #pragma unroll
    for (int k = 0; k < 32; ++k) acc[k] = b2[k];

    #pragma unroll 4
    for (int j = 0; j < HIDDEN; ++j) {
        float h = b1[j];
        h = fmaf(f0, W1[j], h);
        h = fmaf(f1, W1[HIDDEN + j], h);
        h = fmaf(f2, W1[2 * HIDDEN + j], h);
        h = fmaxf(h, 0.0f);                       // relu
        #pragma unroll
        for (int k = 0; k < 32; ++k)
            acc[k] = fmaf(h, W2[j * 32 + k], acc[k]);
    }

    float o = b3[0];
    #pragma unroll
    for (int k = 0; k < 32; ++k)
        o = fmaf(fmaxf(acc[k], 0.0f), W3[k], o);  // relu + final dot

    out[row] = 1.0f / (1.0f + __expf(-o));        // sigmoid
}

extern "C" void kernel_launch(void* const* d_in, const int* in_sizes, int n_in,
                              void* d_out, int out_size, void* d_ws, size_t ws_size,
                              hipStream_t stream) {
    const float* hist = (const float*)d_in[0];
    const float* W1   = (const float*)d_in[1];
    const float* b1   = (const float*)d_in[2];
    const float* W2   = (const float*)d_in[3];
    const float* b2   = (const float*)d_in[4];
    const float* W3   = (const float*)d_in[5];
    const float* b3   = (const float*)d_in[6];
    float* out = (float*)d_out;

    const int threads = 256;
    const int blocks  = BATCH / threads;  // 1024
    competence_kernel<<<blocks, threads, 0, stream>>>(
        hist, W1, b1, W2, b2, W3, b3, out);
}